// Round 4
// baseline (168.684 us; speedup 1.0000x reference)
//
#include <hip/hip_runtime.h>

#define DIM_ 1024
#define HEADS_ 16
#define HD_ 64
#define T_ 2048
#define BATCH_ 2
#define QKVN_ 3072

typedef unsigned short u16;
typedef float f32x4 __attribute__((ext_vector_type(4)));
typedef short s16x8 __attribute__((ext_vector_type(8)));
typedef unsigned short u16x4 __attribute__((ext_vector_type(4)));

__device__ __forceinline__ u16 f2bf(float f) {
  unsigned u = __float_as_uint(f);
  u += 0x7fffu + ((u >> 16) & 1u);
  return (u16)(u >> 16);
}

__device__ __forceinline__ float fexp2(float x) {
  float r;
  asm("v_exp_f32 %0, %1" : "=v"(r) : "v"(x));
  return r;
}

// ---------------- fp32 -> bf16 conversion ----------------
__global__ __launch_bounds__(256) void cvt_f32_bf16(const float* __restrict__ in,
                                                    u16* __restrict__ out, int n4) {
  int i = blockIdx.x * 256 + threadIdx.x;
  if (i >= n4) return;
  float4 v = reinterpret_cast<const float4*>(in)[i];
  u16x4 o;
  o.x = f2bf(v.x); o.y = f2bf(v.y); o.z = f2bf(v.z); o.w = f2bf(v.w);
  reinterpret_cast<u16x4*>(out)[i] = o;
}

// ---------------- async global->LDS helper ----------------
__device__ __forceinline__ void gld_lds16(const void* g, void* l) {
  auto gp = (__attribute__((address_space(1))) char*)(unsigned long long)g;
  auto lp = (__attribute__((address_space(3))) char*)(unsigned int)(unsigned long long)l;
  __builtin_amdgcn_global_load_lds(gp, lp, 16, 0, 0);
}

// ---------------- GEMM: C[M][N] = A[M][K] * B[N][K]^T (bf16 in, fp32 acc) ----------------
template <int OUTF32>
__global__ __launch_bounds__(256) void gemm_bt(const u16* __restrict__ A,
                                               const u16* __restrict__ B,
                                               void* __restrict__ Cv,
                                               int M, int N, int K) {
  __shared__ __align__(16) u16 As[128 * 32];
  __shared__ __align__(16) u16 Bs[128 * 32];
  const int tid = threadIdx.x;
  const int lane = tid & 63;
  const int w = tid >> 6;
  const int wr = w >> 1, wc = w & 1;
  const int lrow = lane & 15, kg = lane >> 4;
  const int nt = blockIdx.x, mt = blockIdx.y;
  const u16* Ag = A + (size_t)(mt * 128) * K;
  const u16* Bg = B + (size_t)(nt * 128) * K;

  f32x4 acc[4][4];
#pragma unroll
  for (int i = 0; i < 4; ++i)
#pragma unroll
    for (int j = 0; j < 4; ++j) {
      f32x4 z = {0.f, 0.f, 0.f, 0.f};
      acc[i][j] = z;
    }

  const int e0 = tid * 8;
  const int row0 = e0 >> 5, kc0 = e0 & 31;
  const int row1 = row0 + 64, kc1 = kc0;
  const int ldsoff0 = (tid & ~63) * 16;
  const int ldsoff1 = (256 + (tid & ~63)) * 16;

  for (int k0 = 0; k0 < K; k0 += 32) {
    gld_lds16(Ag + (size_t)row0 * K + k0 + kc0, (char*)As + ldsoff0);
    gld_lds16(Ag + (size_t)row1 * K + k0 + kc1, (char*)As + ldsoff1);
    gld_lds16(Bg + (size_t)row0 * K + k0 + kc0, (char*)Bs + ldsoff0);
    gld_lds16(Bg + (size_t)row1 * K + k0 + kc1, (char*)Bs + ldsoff1);
    __syncthreads();
    s16x8 a[4], b[4];
#pragma unroll
    for (int mf = 0; mf < 4; ++mf)
      a[mf] = *(const s16x8*)&As[(wr * 64 + mf * 16 + lrow) * 32 + 8 * kg];
#pragma unroll
    for (int nf = 0; nf < 4; ++nf)
      b[nf] = *(const s16x8*)&Bs[(wc * 64 + nf * 16 + lrow) * 32 + 8 * kg];
#pragma unroll
    for (int mf = 0; mf < 4; ++mf)
#pragma unroll
      for (int nf = 0; nf < 4; ++nf)
        acc[mf][nf] = __builtin_amdgcn_mfma_f32_16x16x32_bf16(a[mf], b[nf], acc[mf][nf], 0, 0, 0);
    __syncthreads();
  }

#pragma unroll
  for (int mf = 0; mf < 4; ++mf)
#pragma unroll
    for (int nf = 0; nf < 4; ++nf)
#pragma unroll
      for (int j = 0; j < 4; ++j) {
        int r = mt * 128 + wr * 64 + mf * 16 + 4 * kg + j;
        int c = nt * 128 + wc * 64 + nf * 16 + lrow;
        float v = acc[mf][nf][j];
        if (OUTF32) ((float*)Cv)[(size_t)r * N + c] = v;
        else        ((u16*)Cv)[(size_t)r * N + c] = f2bf(v);
      }
}

// ---------------- V transpose: vt[b][h][d][t] = qkv[b*T+t][2048 + h*64 + d] ----------------
__global__ __launch_bounds__(256) void transpose_v(const u16* __restrict__ qkv,
                                                   u16* __restrict__ vt) {
  const int tt = blockIdx.x, bh = blockIdx.y;
  const int b = bh >> 4, h = bh & 15;
  const int d = threadIdx.x & 63;
  const int t16 = threadIdx.x >> 6;
  const int tbase = tt * 64 + t16 * 16;
  u16 tmp[16];
#pragma unroll
  for (int i = 0; i < 16; ++i)
    tmp[i] = qkv[(size_t)(b * T_ + tbase + i) * QKVN_ + 2048 + h * 64 + d];
  u16* dst = vt + (size_t)(bh * 64 + d) * T_ + tbase;
  *(s16x8*)dst = *(const s16x8*)tmp;
  *(s16x8*)(dst + 8) = *(const s16x8*)(tmp + 8);
}

// ---------------- causal flash attention ----------------
// 512 blocks (qt descending x 32 bh), 512 threads = 8 waves x 16 q-rows = 128 rows.
// LDS: split-plane conflict-free layouts, 48 KB total -> 3 blocks/CU.
// Ks/Vs: [buf][ksl][row][32] staged linearly from pre-swizzled global source.
// plds:  per-wave [ksl][16][32] with kg-XOR swizzle (same involution both sides).
__global__ __launch_bounds__(512, 6) void attn_fwd(const u16* __restrict__ qkv,
                                                   const u16* __restrict__ vt,
                                                   u16* __restrict__ o) {
  const int gid = blockIdx.x;
  const int qt = 15 - (gid >> 5);      // long blocks first
  const int bh = gid & 31;
  const int b = bh >> 4, h = bh & 15;
  const int tid = threadIdx.x;
  const int w = tid >> 6, lane = tid & 63;
  const int lrow = lane & 15, kg = lane >> 4;
  const int qbase = qt * 128;
  const int wrow0 = qbase + w * 16;    // this wave's 16 q rows
  const int wmax = wrow0 + 15;
  const int diag = wmax & ~63;         // the single kv tile needing a causal mask

  __shared__ __align__(16) u16 Ks[2][4096];   // [buf][ksl*2048 + row*32 + col]
  __shared__ __align__(16) u16 Vs[2][4096];   // [buf][ksl*2048 + d*32 + kvcol]
  __shared__ __align__(16) u16 plds[8][1024]; // [wave][ksl*512 + row*32 + col] (swizzled)

  // staging: thread tid writes LDS bytes [16*tid, 16*tid+16) -> pre-swizzled source
  const int ksl_s = tid >> 8;          // 0..1
  const int row_s = (tid >> 2) & 63;   // 0..63
  const int col_s = (tid & 3) * 8;     // elems
  const u16* Kbase = qkv + (size_t)(b * T_) * QKVN_ + 1024 + h * 64;
  const u16* Vbase = vt + (size_t)(bh * 64) * T_;
  const u16* Ksrc0 = Kbase + (size_t)row_s * QKVN_ + ksl_s * 32 + col_s;  // + kvb*QKVN_
  const u16* Vsrc0 = Vbase + (size_t)row_s * T_ + ksl_s * 32 + col_s;     // + kvb

  // Q fragments (rows wrow0 + lrow)
  s16x8 aq0, aq1;
  {
    const size_t qo = (size_t)(b * T_ + wrow0 + lrow) * QKVN_ + h * 64 + 8 * kg;
    aq0 = *(const s16x8*)&qkv[qo];
    aq1 = *(const s16x8*)&qkv[qo + 32];
  }

  f32x4 oacc[4];
#pragma unroll
  for (int nf = 0; nf < 4; ++nf) {
    f32x4 z = {0.f, 0.f, 0.f, 0.f};
    oacc[nf] = z;
  }
  float mrun[4], lrun[4];
#pragma unroll
  for (int j = 0; j < 4; ++j) { mrun[j] = -__builtin_inff(); lrun[j] = 0.0f; }

  const float CEXP = 0.18033688011112042f;  // (1/8) * log2(e)
  const int nkt = 2 * qt + 2;

  // per-lane LDS read offsets (bytes)
  char* const pb = (char*)&plds[w][0];
  const int psw = (lrow >> 2) << 4;                 // read-side swizzle
  const int prd = lrow * 64 + (16 * kg ^ psw);      // within-plane byte offset
  const int fragoff = (lrow * 32 + 8 * kg) * 2;     // K/V frag byte offset within (ksl,nf) block

  // prologue: stage tile 0 (linear LDS write = conflict-free)
  s16x8 kr, vr;
  kr = *(const s16x8*)Ksrc0;
  vr = *(const s16x8*)Vsrc0;
  *(s16x8*)((char*)&Ks[0][0] + tid * 16) = kr;
  *(s16x8*)((char*)&Vs[0][0] + tid * 16) = vr;

  int cur = 0;
  for (int kt = 0; kt < nkt; ++kt) {
    const int kvb = kt * 64;
    const bool havenext = (kt + 1 < nkt);
    if (havenext) {                       // issue next-tile loads early (T14)
      kr = *(const s16x8*)(Ksrc0 + (size_t)(kvb + 64) * QKVN_);
      vr = *(const s16x8*)(Vsrc0 + kvb + 64);
    }
    __syncthreads();                      // buf[cur] visible to all waves

    if (kvb <= wmax) {
      const char* Kc = (const char*)&Ks[cur][0];
      const char* Vc = (const char*)&Vs[cur][0];
      // ---- QK^T ----
      f32x4 sacc[4];
#pragma unroll
      for (int nf = 0; nf < 4; ++nf) {
        f32x4 z = {0.f, 0.f, 0.f, 0.f};
        sacc[nf] = z;
      }
      __builtin_amdgcn_s_setprio(1);
#pragma unroll
      for (int nf = 0; nf < 4; ++nf) {
        const s16x8 kf0 = *(const s16x8*)(Kc + nf * 1024 + fragoff);
        const s16x8 kf1 = *(const s16x8*)(Kc + 4096 + nf * 1024 + fragoff);
        sacc[nf] = __builtin_amdgcn_mfma_f32_16x16x32_bf16(aq0, kf0, sacc[nf], 0, 0, 0);
        sacc[nf] = __builtin_amdgcn_mfma_f32_16x16x32_bf16(aq1, kf1, sacc[nf], 0, 0, 0);
      }
      __builtin_amdgcn_s_setprio(0);

      // ---- causal mask (diagonal tile only; wave-uniform branch) ----
      if (kvb == diag) {
        const int r = wrow0 + 4 * kg;
#pragma unroll
        for (int nf = 0; nf < 4; ++nf) {
          const int cg = kvb + nf * 16 + lrow;
#pragma unroll
          for (int j = 0; j < 4; ++j)
            if (cg > r + j) sacc[nf][j] = -__builtin_inff();
        }
      }

      // ---- online softmax (exp2 domain, raw scores) ----
      float mj[4];
#pragma unroll
      for (int j = 0; j < 4; ++j)
        mj[j] = fmaxf(fmaxf(sacc[0][j], sacc[1][j]), fmaxf(sacc[2][j], sacc[3][j]));
#pragma unroll
      for (int off = 1; off < 16; off <<= 1)
#pragma unroll
        for (int j = 0; j < 4; ++j)
          mj[j] = fmaxf(mj[j], __shfl_xor(mj[j], off, 16));

      bool needfull = false;
#pragma unroll
      for (int j = 0; j < 4; ++j)
        needfull |= !((mj[j] - mrun[j]) * CEXP <= 8.0f);
      if (__any(needfull)) {
#pragma unroll
        for (int j = 0; j < 4; ++j) {
          float newm = fmaxf(mrun[j], mj[j]);
          float sc = fexp2((mrun[j] - newm) * CEXP);
          mrun[j] = newm;
          lrun[j] *= sc;
#pragma unroll
          for (int nf = 0; nf < 4; ++nf) oacc[nf][j] *= sc;
        }
      }
      float msc[4];
#pragma unroll
      for (int j = 0; j < 4; ++j) msc[j] = mrun[j] * CEXP;

      float rs[4] = {0.f, 0.f, 0.f, 0.f};
#pragma unroll
      for (int nf = 0; nf < 4; ++nf) {
        const int pcol2 = ((nf & 1) * 16 + lrow) * 2;
        const int pbase = (nf >> 1) * 1024;
#pragma unroll
        for (int j = 0; j < 4; ++j) {
          float p = fexp2(__builtin_fmaf(sacc[nf][j], CEXP, -msc[j]));
          rs[j] += p;
          // write-side swizzle: row = 4kg+j, byte = row*64 + (col*2 ^ (kg<<4))
          *(u16*)(pb + pbase + (4 * kg + j) * 64 + (pcol2 ^ (kg << 4))) = f2bf(p);
        }
      }
#pragma unroll
      for (int off = 1; off < 16; off <<= 1)
#pragma unroll
        for (int j = 0; j < 4; ++j)
          rs[j] += __shfl_xor(rs[j], off, 16);
#pragma unroll
      for (int j = 0; j < 4; ++j) lrun[j] += rs[j];

      // ---- P @ V ----
      const s16x8 pa0 = *(const s16x8*)(pb + prd);
      const s16x8 pa1 = *(const s16x8*)(pb + 1024 + prd);
      __builtin_amdgcn_s_setprio(1);
#pragma unroll
      for (int nf = 0; nf < 4; ++nf) {
        const s16x8 vf0 = *(const s16x8*)(Vc + nf * 1024 + fragoff);
        const s16x8 vf1 = *(const s16x8*)(Vc + 4096 + nf * 1024 + fragoff);
        oacc[nf] = __builtin_amdgcn_mfma_f32_16x16x32_bf16(pa0, vf0, oacc[nf], 0, 0, 0);
        oacc[nf] = __builtin_amdgcn_mfma_f32_16x16x32_bf16(pa1, vf1, oacc[nf], 0, 0, 0);
      }
      __builtin_amdgcn_s_setprio(0);
    }

    if (havenext) {                       // write-late into the other buffer
      *(s16x8*)((char*)&Ks[cur ^ 1][0] + tid * 16) = kr;
      *(s16x8*)((char*)&Vs[cur ^ 1][0] + tid * 16) = vr;
    }
    cur ^= 1;
  }

#pragma unroll
  for (int nf = 0; nf < 4; ++nf)
#pragma unroll
    for (int j = 0; j < 4; ++j) {
      float v = oacc[nf][j] / lrun[j];
      const int t = wrow0 + 4 * kg + j;
      o[(size_t)(b * T_ + t) * DIM_ + h * 64 + nf * 16 + lrow] = f2bf(v);
    }
}

// ---------------- launch ----------------
extern "C" void kernel_launch(void* const* d_in, const int* in_sizes, int n_in,
                              void* d_out, int out_size, void* d_ws, size_t ws_size,
                              hipStream_t stream) {
  const float* x = (const float*)d_in[0];
  const float* w_qkv = (const float*)d_in[1];
  const float* w_out = (const float*)d_in[2];
  char* ws = (char*)d_ws;
  u16* xb    = (u16*)(ws + 0);          // 8,388,608
  u16* wqkvb = (u16*)(ws + 8388608);    // 6,291,456
  u16* woutb = (u16*)(ws + 14680064);   // 2,097,152
  u16* qkvb  = (u16*)(ws + 16777216);   // 25,165,824
  u16* vtb   = (u16*)(ws + 41943040);   // 8,388,608
  u16* attno = (u16*)(ws + 50331648);   // 8,388,608

  cvt_f32_bf16<<<4096, 256, 0, stream>>>(x, xb, 1048576);
  cvt_f32_bf16<<<3072, 256, 0, stream>>>(w_qkv, wqkvb, 786432);
  cvt_f32_bf16<<<1024, 256, 0, stream>>>(w_out, woutb, 262144);
  gemm_bt<0><<<dim3(24, 32), 256, 0, stream>>>(xb, wqkvb, qkvb, 4096, 3072, 1024);
  transpose_v<<<dim3(32, 32), 256, 0, stream>>>(qkvb, vtb);
  attn_fwd<<<512, 512, 0, stream>>>(qkvb, vtb, attno);
  gemm_bt<1><<<dim3(8, 32), 256, 0, stream>>>(attno, woutb, (float*)d_out, 4096, 1024, 1024);
}

// Round 5
// 152.109 us; speedup vs baseline: 1.1090x; 1.1090x over previous
//
#include <hip/hip_runtime.h>

#define DIM_ 1024
#define HEADS_ 16
#define HD_ 64
#define T_ 2048
#define BATCH_ 2
#define QKVN_ 3072

typedef unsigned short u16;
typedef unsigned int u32;
typedef float f32x4 __attribute__((ext_vector_type(4)));
typedef float f32x16 __attribute__((ext_vector_type(16)));
typedef short s16x8 __attribute__((ext_vector_type(8)));
typedef unsigned short u16x4 __attribute__((ext_vector_type(4)));

__device__ __forceinline__ u16 f2bf(float f) {
  unsigned u = __float_as_uint(f);
  u += 0x7fffu + ((u >> 16) & 1u);
  return (u16)(u >> 16);
}

__device__ __forceinline__ float fexp2(float x) {
  float r;
  asm("v_exp_f32 %0, %1" : "=v"(r) : "v"(x));
  return r;
}

__device__ __forceinline__ u32 cvtpk(float a, float b) {
  u32 r;
  asm("v_cvt_pk_bf16_f32 %0, %1, %2" : "=v"(r) : "v"(a), "v"(b));
  return r;
}

// ---------------- fp32 -> bf16 conversion ----------------
__global__ __launch_bounds__(256) void cvt_f32_bf16(const float* __restrict__ in,
                                                    u16* __restrict__ out, int n4) {
  int i = blockIdx.x * 256 + threadIdx.x;
  if (i >= n4) return;
  float4 v = reinterpret_cast<const float4*>(in)[i];
  u16x4 o;
  o.x = f2bf(v.x); o.y = f2bf(v.y); o.z = f2bf(v.z); o.w = f2bf(v.w);
  reinterpret_cast<u16x4*>(out)[i] = o;
}

// ---------------- async global->LDS helper ----------------
__device__ __forceinline__ void gld_lds16(const void* g, void* l) {
  auto gp = (__attribute__((address_space(1))) char*)(unsigned long long)g;
  auto lp = (__attribute__((address_space(3))) char*)(unsigned int)(unsigned long long)l;
  __builtin_amdgcn_global_load_lds(gp, lp, 16, 0, 0);
}

// ---------------- GEMM: C[M][N] = A[M][K] * B[N][K]^T (bf16 in, fp32 acc) ----------------
template <int OUTF32>
__global__ __launch_bounds__(256) void gemm_bt(const u16* __restrict__ A,
                                               const u16* __restrict__ B,
                                               void* __restrict__ Cv,
                                               int M, int N, int K) {
  __shared__ __align__(16) u16 As[128 * 32];
  __shared__ __align__(16) u16 Bs[128 * 32];
  const int tid = threadIdx.x;
  const int lane = tid & 63;
  const int w = tid >> 6;
  const int wr = w >> 1, wc = w & 1;
  const int lrow = lane & 15, kg = lane >> 4;
  const int nt = blockIdx.x, mt = blockIdx.y;
  const u16* Ag = A + (size_t)(mt * 128) * K;
  const u16* Bg = B + (size_t)(nt * 128) * K;

  f32x4 acc[4][4];
#pragma unroll
  for (int i = 0; i < 4; ++i)
#pragma unroll
    for (int j = 0; j < 4; ++j) {
      f32x4 z = {0.f, 0.f, 0.f, 0.f};
      acc[i][j] = z;
    }

  const int e0 = tid * 8;
  const int row0 = e0 >> 5, kc0 = e0 & 31;
  const int row1 = row0 + 64, kc1 = kc0;
  const int ldsoff0 = (tid & ~63) * 16;
  const int ldsoff1 = (256 + (tid & ~63)) * 16;

  for (int k0 = 0; k0 < K; k0 += 32) {
    gld_lds16(Ag + (size_t)row0 * K + k0 + kc0, (char*)As + ldsoff0);
    gld_lds16(Ag + (size_t)row1 * K + k0 + kc1, (char*)As + ldsoff1);
    gld_lds16(Bg + (size_t)row0 * K + k0 + kc0, (char*)Bs + ldsoff0);
    gld_lds16(Bg + (size_t)row1 * K + k0 + kc1, (char*)Bs + ldsoff1);
    __syncthreads();
    s16x8 a[4], b[4];
#pragma unroll
    for (int mf = 0; mf < 4; ++mf)
      a[mf] = *(const s16x8*)&As[(wr * 64 + mf * 16 + lrow) * 32 + 8 * kg];
#pragma unroll
    for (int nf = 0; nf < 4; ++nf)
      b[nf] = *(const s16x8*)&Bs[(wc * 64 + nf * 16 + lrow) * 32 + 8 * kg];
#pragma unroll
    for (int mf = 0; mf < 4; ++mf)
#pragma unroll
      for (int nf = 0; nf < 4; ++nf)
        acc[mf][nf] = __builtin_amdgcn_mfma_f32_16x16x32_bf16(a[mf], b[nf], acc[mf][nf], 0, 0, 0);
    __syncthreads();
  }

#pragma unroll
  for (int mf = 0; mf < 4; ++mf)
#pragma unroll
    for (int nf = 0; nf < 4; ++nf)
#pragma unroll
      for (int j = 0; j < 4; ++j) {
        int r = mt * 128 + wr * 64 + mf * 16 + 4 * kg + j;
        int c = nt * 128 + wc * 64 + nf * 16 + lrow;
        float v = acc[mf][nf][j];
        if (OUTF32) ((float*)Cv)[(size_t)r * N + c] = v;
        else        ((u16*)Cv)[(size_t)r * N + c] = f2bf(v);
      }
}

// ---------------- V transpose: vt[b][h][d][t] = qkv[b*T+t][2048 + h*64 + d] ----------------
__global__ __launch_bounds__(256) void transpose_v(const u16* __restrict__ qkv,
                                                   u16* __restrict__ vt) {
  const int tt = blockIdx.x, bh = blockIdx.y;
  const int b = bh >> 4, h = bh & 15;
  const int d = threadIdx.x & 63;
  const int t16 = threadIdx.x >> 6;
  const int tbase = tt * 64 + t16 * 16;
  u16 tmp[16];
#pragma unroll
  for (int i = 0; i < 16; ++i)
    tmp[i] = qkv[(size_t)(b * T_ + tbase + i) * QKVN_ + 2048 + h * 64 + d];
  u16* dst = vt + (size_t)(bh * 64 + d) * T_ + tbase;
  *(s16x8*)dst = *(const s16x8*)tmp;
  *(s16x8*)(dst + 8) = *(const s16x8*)(tmp + 8);
}

// ---------------- causal flash attention (swapped-operand 32x32, in-register softmax) ----
// 512 blocks (16 qt desc x 32 bh), 256 threads = 4 waves x 32 q-rows = 128 rows.
// K/V tiles 64x64 double-buffered in LDS (slot^row&7 swizzle), P never touches LDS.
__global__ __launch_bounds__(256, 4) void attn_fwd(const u16* __restrict__ qkv,
                                                   const u16* __restrict__ vt,
                                                   u16* __restrict__ o) {
  const int gid = blockIdx.x;
  const int qt = 15 - (gid >> 5);      // long blocks first
  const int bh = gid & 31;
  const int b = bh >> 4, h = bh & 15;
  const int tid = threadIdx.x;
  const int w = tid >> 6, lane = tid & 63;
  const int l31 = lane & 31, hi = lane >> 5;
  const int qbase = qt * 128;
  const int wrow0 = qbase + w * 32;    // this wave's 32 q rows
  const int wmax = wrow0 + 31;
  const int woff = wrow0 & 63;         // 0 or 32
  const int diag = wrow0 & ~63;        // kv tile needing the causal mask

  __shared__ __align__(16) u16 Ks[2][4096];   // [buf] 64 rows x 128 B, slot-swizzled
  __shared__ __align__(16) u16 Vs[2][4096];   // [buf] 64 d-rows x 128 B (kv), swizzled

  // ---- staging coords: 2 x 16B chunks each for K and V per thread ----
  const int r0 = tid >> 3, s0 = tid & 7;            // f = tid
  const int r1 = (256 + tid) >> 3, s1 = tid & 7;    // f = 256+tid
  const u16* Kbase = qkv + (size_t)(b * T_) * QKVN_ + 1024 + h * 64;
  const u16* Vbase = vt + (size_t)(bh * 64) * T_;
  const u16* Kg0 = Kbase + (size_t)r0 * QKVN_ + s0 * 8;
  const u16* Kg1 = Kbase + (size_t)r1 * QKVN_ + s1 * 8;
  const u16* Vg0 = Vbase + (size_t)r0 * T_ + s0 * 8;
  const u16* Vg1 = Vbase + (size_t)r1 * T_ + s1 * 8;
  const int kd0 = r0 * 128 + ((s0 ^ (r0 & 7)) << 4);   // LDS byte offsets
  const int kd1 = r1 * 128 + ((s1 ^ (r1 & 7)) << 4);

  // ---- Q fragments: lane (l31,hi) holds Q[wrow0+l31][16*ksl + 8*hi .. +8] ----
  s16x8 qf[4];
  {
    const u16* qp = qkv + (size_t)(b * T_ + wrow0 + l31) * QKVN_ + h * 64 + 8 * hi;
#pragma unroll
    for (int ksl = 0; ksl < 4; ++ksl)
      qf[ksl] = *(const s16x8*)(qp + 16 * ksl);
  }

  // ---- per-lane fragment read helpers (byte offsets) ----
  const int rbyte = l31 * 128;
  const int xsw = l31 & 7;

  f32x16 o0v, o1v;
#pragma unroll
  for (int r = 0; r < 16; ++r) { o0v[r] = 0.f; o1v[r] = 0.f; }
  float mrun = -__builtin_inff(), lrun = 0.0f;

  const float CEXP = 0.18033688011112042f;  // (1/8) * log2(e)
  const int nkt = 2 * qt + 2;

  // prologue: stage tile 0
  s16x8 kr0, kr1, vr0, vr1;
  kr0 = *(const s16x8*)Kg0;
  kr1 = *(const s16x8*)Kg1;
  vr0 = *(const s16x8*)Vg0;
  vr1 = *(const s16x8*)Vg1;
  *(s16x8*)((char*)&Ks[0][0] + kd0) = kr0;
  *(s16x8*)((char*)&Ks[0][0] + kd1) = kr1;
  *(s16x8*)((char*)&Vs[0][0] + kd0) = vr0;
  *(s16x8*)((char*)&Vs[0][0] + kd1) = vr1;

  int cur = 0;
  for (int kt = 0; kt < nkt; ++kt) {
    const int kvb = kt * 64;
    const bool havenext = (kt + 1 < nkt);
    if (havenext) {                       // T14: issue next-tile loads early
      const int nb = kvb + 64;
      kr0 = *(const s16x8*)(Kg0 + (size_t)nb * QKVN_);
      kr1 = *(const s16x8*)(Kg1 + (size_t)nb * QKVN_);
      vr0 = *(const s16x8*)(Vg0 + nb);
      vr1 = *(const s16x8*)(Vg1 + nb);
    }
    __syncthreads();                      // buf[cur] visible to all waves

    if (kvb <= wmax) {
      const char* Kc = (const char*)&Ks[cur][0];
      const char* Vc = (const char*)&Vs[cur][0];
      const bool two = !(kvb == diag && woff == 0);  // kvs=1 live?

      // ---- QK^T (swapped): S[kv][q], lane holds q = wrow0+l31 ----
      f32x16 s0v, s1v;
#pragma unroll
      for (int r = 0; r < 16; ++r) { s0v[r] = 0.f; s1v[r] = 0.f; }
      __builtin_amdgcn_s_setprio(1);
#pragma unroll
      for (int ksl = 0; ksl < 4; ++ksl) {
        const s16x8 kf = *(const s16x8*)(Kc + rbyte + (((2 * ksl + hi) ^ xsw) << 4));
        s0v = __builtin_amdgcn_mfma_f32_32x32x16_bf16(kf, qf[ksl], s0v, 0, 0, 0);
      }
      if (two) {
#pragma unroll
        for (int ksl = 0; ksl < 4; ++ksl) {
          const s16x8 kf = *(const s16x8*)(Kc + 4096 + rbyte + (((2 * ksl + hi) ^ xsw) << 4));
          s1v = __builtin_amdgcn_mfma_f32_32x32x16_bf16(kf, qf[ksl], s1v, 0, 0, 0);
        }
      }
      __builtin_amdgcn_s_setprio(0);

      // ---- causal mask on diagonal tile: kv_local > woff + l31 -> -inf ----
      if (kvb == diag) {
        const int thr = woff + l31;
#pragma unroll
        for (int r = 0; r < 16; ++r) {
          const int kvl = 4 * hi + (r & 3) + 8 * (r >> 2);
          if (kvl > thr) s0v[r] = -__builtin_inff();
          if (two && kvl + 32 > thr) s1v[r] = -__builtin_inff();
        }
      }

      // ---- online softmax, fully per-lane (q = l31) ----
      float mloc = s0v[0];
#pragma unroll
      for (int r = 1; r < 16; ++r) mloc = fmaxf(mloc, s0v[r]);
      if (two) {
#pragma unroll
        for (int r = 0; r < 16; ++r) mloc = fmaxf(mloc, s1v[r]);
      }
      mloc = fmaxf(mloc, __shfl_xor(mloc, 32));

      const bool needfull = !((mloc - mrun) * CEXP <= 8.0f);
      if (__any(needfull)) {
        const float newm = fmaxf(mrun, mloc);
        const float sc = fexp2((mrun - newm) * CEXP);
        mrun = newm;
        lrun *= sc;
        o0v *= sc;
        o1v *= sc;
      }
      const float msc = mrun * CEXP;

      float rs = 0.0f;
      u32 pd0[8], pd1[8];
#pragma unroll
      for (int ri = 0; ri < 8; ++ri) {
        const float p0 = fexp2(__builtin_fmaf(s0v[2 * ri], CEXP, -msc));
        const float p1 = fexp2(__builtin_fmaf(s0v[2 * ri + 1], CEXP, -msc));
        rs += p0 + p1;
        pd0[ri] = cvtpk(p0, p1);
      }
      if (two) {
#pragma unroll
        for (int ri = 0; ri < 8; ++ri) {
          const float p0 = fexp2(__builtin_fmaf(s1v[2 * ri], CEXP, -msc));
          const float p1 = fexp2(__builtin_fmaf(s1v[2 * ri + 1], CEXP, -msc));
          rs += p0 + p1;
          pd1[ri] = cvtpk(p0, p1);
        }
      }
      rs += __shfl_xor(rs, 32);
      lrun += rs;

      // ---- build PV B-fragments in-register (permlane32_swap) and accumulate ----
      __builtin_amdgcn_s_setprio(1);
#pragma unroll
      for (int kk = 0; kk < 4; ++kk) {
        if (kk >= 2 && !two) break;
        u32 x0, y0, x1, y1;
        if (kk == 0)      { x0 = pd0[0]; y0 = pd0[2]; x1 = pd0[1]; y1 = pd0[3]; }
        else if (kk == 1) { x0 = pd0[4]; y0 = pd0[6]; x1 = pd0[5]; y1 = pd0[7]; }
        else if (kk == 2) { x0 = pd1[0]; y0 = pd1[2]; x1 = pd1[1]; y1 = pd1[3]; }
        else              { x0 = pd1[4]; y0 = pd1[6]; x1 = pd1[5]; y1 = pd1[7]; }
        asm volatile("v_permlane32_swap_b32 %0, %1" : "+v"(x0), "+v"(y0));
        asm volatile("v_permlane32_swap_b32 %0, %1" : "+v"(x1), "+v"(y1));
        u32 pw[4] = {x0, x1, y0, y1};
        const s16x8 pf = *(const s16x8*)pw;
        const s16x8 vf0 = *(const s16x8*)(Vc + rbyte + (((2 * kk + hi) ^ xsw) << 4));
        const s16x8 vf1 = *(const s16x8*)(Vc + 4096 + rbyte + (((2 * kk + hi) ^ xsw) << 4));
        o0v = __builtin_amdgcn_mfma_f32_32x32x16_bf16(vf0, pf, o0v, 0, 0, 0);
        o1v = __builtin_amdgcn_mfma_f32_32x32x16_bf16(vf1, pf, o1v, 0, 0, 0);
      }
      __builtin_amdgcn_s_setprio(0);
    }

    if (havenext) {                       // write-late into the other buffer
      const int nxt = cur ^ 1;
      *(s16x8*)((char*)&Ks[nxt][0] + kd0) = kr0;
      *(s16x8*)((char*)&Ks[nxt][0] + kd1) = kr1;
      *(s16x8*)((char*)&Vs[nxt][0] + kd0) = vr0;
      *(s16x8*)((char*)&Vs[nxt][0] + kd1) = vr1;
    }
    cur ^= 1;
  }

  // ---- epilogue: O^T in regs, q = l31 per lane; d = 32*ds + 4*hi + (r&3) + 8*(r>>2) ----
  const float linv = 1.0f / lrun;
  u16* orow = o + (size_t)(b * T_ + wrow0 + l31) * DIM_ + h * 64;
#pragma unroll
  for (int ri = 0; ri < 8; ++ri) {
    const int dbase0 = 4 * hi + 8 * (ri >> 1) + 2 * (ri & 1);
    const u32 w0 = cvtpk(o0v[2 * ri] * linv, o0v[2 * ri + 1] * linv);
    const u32 w1 = cvtpk(o1v[2 * ri] * linv, o1v[2 * ri + 1] * linv);
    *(u32*)(orow + dbase0) = w0;
    *(u32*)(orow + 32 + dbase0) = w1;
  }
}

// ---------------- launch ----------------
extern "C" void kernel_launch(void* const* d_in, const int* in_sizes, int n_in,
                              void* d_out, int out_size, void* d_ws, size_t ws_size,
                              hipStream_t stream) {
  const float* x = (const float*)d_in[0];
  const float* w_qkv = (const float*)d_in[1];
  const float* w_out = (const float*)d_in[2];
  char* ws = (char*)d_ws;
  u16* xb    = (u16*)(ws + 0);          // 8,388,608
  u16* wqkvb = (u16*)(ws + 8388608);    // 6,291,456
  u16* woutb = (u16*)(ws + 14680064);   // 2,097,152
  u16* qkvb  = (u16*)(ws + 16777216);   // 25,165,824
  u16* vtb   = (u16*)(ws + 41943040);   // 8,388,608
  u16* attno = (u16*)(ws + 50331648);   // 8,388,608

  cvt_f32_bf16<<<4096, 256, 0, stream>>>(x, xb, 1048576);
  cvt_f32_bf16<<<3072, 256, 0, stream>>>(w_qkv, wqkvb, 786432);
  cvt_f32_bf16<<<1024, 256, 0, stream>>>(w_out, woutb, 262144);
  gemm_bt<0><<<dim3(24, 32), 256, 0, stream>>>(xb, wqkvb, qkvb, 4096, 3072, 1024);
  transpose_v<<<dim3(32, 32), 256, 0, stream>>>(qkvb, vtb);
  attn_fwd<<<512, 256, 0, stream>>>(qkvb, vtb, attno);
  gemm_bt<1><<<dim3(8, 32), 256, 0, stream>>>(attno, woutb, (float*)d_out, 4096, 1024, 1024);
}

// Round 6
// 131.837 us; speedup vs baseline: 1.2795x; 1.1538x over previous
//
#include <hip/hip_runtime.h>

#define DIM_ 1024
#define HEADS_ 16
#define HD_ 64
#define T_ 2048
#define BATCH_ 2
#define QKVN_ 3072

typedef unsigned short u16;
typedef unsigned int u32;
typedef float f32x4 __attribute__((ext_vector_type(4)));
typedef float f32x16 __attribute__((ext_vector_type(16)));
typedef short s16x8 __attribute__((ext_vector_type(8)));
typedef unsigned short u16x4 __attribute__((ext_vector_type(4)));

__device__ __forceinline__ u16 f2bf(float f) {
  unsigned u = __float_as_uint(f);
  u += 0x7fffu + ((u >> 16) & 1u);
  return (u16)(u >> 16);
}

__device__ __forceinline__ float fexp2(float x) {
  float r;
  asm("v_exp_f32 %0, %1" : "=v"(r) : "v"(x));
  return r;
}

__device__ __forceinline__ u32 cvtpk(float a, float b) {
  u32 r;
  asm("v_cvt_pk_bf16_f32 %0, %1, %2" : "=v"(r) : "v"(a), "v"(b));
  return r;
}

// ---------------- fp32 -> bf16 conversion ----------------
__global__ __launch_bounds__(256) void cvt_f32_bf16(const float* __restrict__ in,
                                                    u16* __restrict__ out, int n4) {
  int i = blockIdx.x * 256 + threadIdx.x;
  if (i >= n4) return;
  float4 v = reinterpret_cast<const float4*>(in)[i];
  u16x4 o;
  o.x = f2bf(v.x); o.y = f2bf(v.y); o.z = f2bf(v.z); o.w = f2bf(v.w);
  reinterpret_cast<u16x4*>(out)[i] = o;
}

// ---------------- async global->LDS helper ----------------
__device__ __forceinline__ void gld_lds16(const void* g, void* l) {
  auto gp = (__attribute__((address_space(1))) char*)(unsigned long long)g;
  auto lp = (__attribute__((address_space(3))) char*)(unsigned int)(unsigned long long)l;
  __builtin_amdgcn_global_load_lds(gp, lp, 16, 0, 0);
}

// ---------------- GEMM: C[M][N] = A[M][K] * B[N][K]^T (bf16 in, fp32 acc) ----------------
template <int OUTF32>
__global__ __launch_bounds__(256) void gemm_bt(const u16* __restrict__ A,
                                               const u16* __restrict__ B,
                                               void* __restrict__ Cv,
                                               int M, int N, int K) {
  __shared__ __align__(16) u16 As[128 * 32];
  __shared__ __align__(16) u16 Bs[128 * 32];
  const int tid = threadIdx.x;
  const int lane = tid & 63;
  const int w = tid >> 6;
  const int wr = w >> 1, wc = w & 1;
  const int lrow = lane & 15, kg = lane >> 4;
  const int nt = blockIdx.x, mt = blockIdx.y;
  const u16* Ag = A + (size_t)(mt * 128) * K;
  const u16* Bg = B + (size_t)(nt * 128) * K;

  f32x4 acc[4][4];
#pragma unroll
  for (int i = 0; i < 4; ++i)
#pragma unroll
    for (int j = 0; j < 4; ++j) {
      f32x4 z = {0.f, 0.f, 0.f, 0.f};
      acc[i][j] = z;
    }

  const int e0 = tid * 8;
  const int row0 = e0 >> 5, kc0 = e0 & 31;
  const int row1 = row0 + 64, kc1 = kc0;
  const int ldsoff0 = (tid & ~63) * 16;
  const int ldsoff1 = (256 + (tid & ~63)) * 16;

  for (int k0 = 0; k0 < K; k0 += 32) {
    gld_lds16(Ag + (size_t)row0 * K + k0 + kc0, (char*)As + ldsoff0);
    gld_lds16(Ag + (size_t)row1 * K + k0 + kc1, (char*)As + ldsoff1);
    gld_lds16(Bg + (size_t)row0 * K + k0 + kc0, (char*)Bs + ldsoff0);
    gld_lds16(Bg + (size_t)row1 * K + k0 + kc1, (char*)Bs + ldsoff1);
    __syncthreads();
    s16x8 a[4], b[4];
#pragma unroll
    for (int mf = 0; mf < 4; ++mf)
      a[mf] = *(const s16x8*)&As[(wr * 64 + mf * 16 + lrow) * 32 + 8 * kg];
#pragma unroll
    for (int nf = 0; nf < 4; ++nf)
      b[nf] = *(const s16x8*)&Bs[(wc * 64 + nf * 16 + lrow) * 32 + 8 * kg];
#pragma unroll
    for (int mf = 0; mf < 4; ++mf)
#pragma unroll
      for (int nf = 0; nf < 4; ++nf)
        acc[mf][nf] = __builtin_amdgcn_mfma_f32_16x16x32_bf16(a[mf], b[nf], acc[mf][nf], 0, 0, 0);
    __syncthreads();
  }

#pragma unroll
  for (int mf = 0; mf < 4; ++mf)
#pragma unroll
    for (int nf = 0; nf < 4; ++nf)
#pragma unroll
      for (int j = 0; j < 4; ++j) {
        int r = mt * 128 + wr * 64 + mf * 16 + 4 * kg + j;
        int c = nt * 128 + wc * 64 + nf * 16 + lrow;
        float v = acc[mf][nf][j];
        if (OUTF32) ((float*)Cv)[(size_t)r * N + c] = v;
        else        ((u16*)Cv)[(size_t)r * N + c] = f2bf(v);
      }
}

// ---------------- V transpose: vt[b][h][d][t] = qkv[b*T+t][2048 + h*64 + d] ----------------
__global__ __launch_bounds__(256) void transpose_v(const u16* __restrict__ qkv,
                                                   u16* __restrict__ vt) {
  const int tt = blockIdx.x, bh = blockIdx.y;
  const int b = bh >> 4, h = bh & 15;
  const int d = threadIdx.x & 63;
  const int t16 = threadIdx.x >> 6;
  const int tbase = tt * 64 + t16 * 16;
  u16 tmp[16];
#pragma unroll
  for (int i = 0; i < 16; ++i)
    tmp[i] = qkv[(size_t)(b * T_ + tbase + i) * QKVN_ + 2048 + h * 64 + d];
  u16* dst = vt + (size_t)(bh * 64 + d) * T_ + tbase;
  *(s16x8*)dst = *(const s16x8*)tmp;
  *(s16x8*)(dst + 8) = *(const s16x8*)(tmp + 8);
}

// ---------------- causal flash attention (swapped 32x32 + kv-split-2) ----------------
// 512 blocks (16 qt desc x 32 bh), 512 threads = 4 q-waves x 2 kv-groups.
// Wave (qw,kvg) owns q rows [qbase+32qw, +32) and kv tiles kt = 2rt+kvg.
// Per round: both parity tiles staged (double-buffered, 64 KB LDS), one barrier.
// End: kvg pairs merge partial (m,l,O) through LDS (reused K/V space).
__global__ __launch_bounds__(512, 4) void attn_fwd(const u16* __restrict__ qkv,
                                                   const u16* __restrict__ vt,
                                                   u16* __restrict__ o) {
  const int gid = blockIdx.x;
  const int qt = 15 - (gid >> 5);      // long blocks first
  const int bh = gid & 31;
  const int b = bh >> 4, h = bh & 15;
  const int tid = threadIdx.x;
  const int lane = tid & 63;
  const int qw = (tid >> 6) & 3;
  const int kvg = tid >> 8;
  const int l31 = lane & 31, hi = lane >> 5;
  const int qbase = qt * 128;
  const int wrow0 = qbase + qw * 32;
  const int wmax = wrow0 + 31;
  const int woff = wrow0 & 63;
  const int diag = wrow0 & ~63;

  // K: smem + buf*16384 + par*8192 ; V: smem + 32768 + buf*16384 + par*8192
  __shared__ __align__(16) char smem[65536];

  // staging: thread -> one 16B chunk in each of {K,V} x {even,odd} tiles
  const int row_s = tid >> 3, slot_s = tid & 7;
  const u16* Kbase = qkv + (size_t)(b * T_) * QKVN_ + 1024 + h * 64;
  const u16* Vbase = vt + (size_t)(bh * 64) * T_;
  const u16* Kg = Kbase + (size_t)row_s * QKVN_ + slot_s * 8;   // + kvb*QKVN_
  const u16* Vg = Vbase + (size_t)row_s * T_ + slot_s * 8;      // + kvb
  const int dst_off = row_s * 128 + ((slot_s ^ (row_s & 7)) << 4);

  // Q fragments: lane (l31,hi) holds Q[wrow0+l31][16*ksl + 8*hi .. +8]
  s16x8 qf[4];
  {
    const u16* qp = qkv + (size_t)(b * T_ + wrow0 + l31) * QKVN_ + h * 64 + 8 * hi;
#pragma unroll
    for (int ksl = 0; ksl < 4; ++ksl)
      qf[ksl] = *(const s16x8*)(qp + 16 * ksl);
  }

  const int rbyte = l31 * 128;
  const int xsw = l31 & 7;

  f32x16 o0v, o1v;
#pragma unroll
  for (int r = 0; r < 16; ++r) { o0v[r] = 0.f; o1v[r] = 0.f; }
  float mrun = -__builtin_inff(), lrun = 0.0f;

  const float CEXP = 0.18033688011112042f;  // (1/8) * log2(e)
  const int nrt = qt + 1;                   // rounds; tiles per round: 2

  // prologue: stage round 0 (tiles 0 and 1)
  *(s16x8*)(smem + dst_off)          = *(const s16x8*)Kg;
  *(s16x8*)(smem + 8192 + dst_off)   = *(const s16x8*)(Kg + (size_t)64 * QKVN_);
  *(s16x8*)(smem + 32768 + dst_off)  = *(const s16x8*)Vg;
  *(s16x8*)(smem + 40960 + dst_off)  = *(const s16x8*)(Vg + 64);

  int cur = 0;
  for (int rt = 0; rt < nrt; ++rt) {
    const int kvb = (2 * rt + kvg) * 64;
    const bool havenext = (rt + 1 < nrt);
    s16x8 ke, ko, ve, vo;
    if (havenext) {                       // T14: issue next-round loads early
      const int nb = (2 * rt + 2) * 64;
      ke = *(const s16x8*)(Kg + (size_t)nb * QKVN_);
      ko = *(const s16x8*)(Kg + (size_t)(nb + 64) * QKVN_);
      ve = *(const s16x8*)(Vg + nb);
      vo = *(const s16x8*)(Vg + nb + 64);
    }
    __syncthreads();                      // round-cur tiles visible

    if (kvb <= wmax) {
      const char* Kc = smem + cur * 16384 + kvg * 8192;
      const char* Vc = smem + 32768 + cur * 16384 + kvg * 8192;
      const bool two = !(kvb == diag && woff == 0);

      // ---- QK^T (swapped): lane holds q = wrow0+l31 ----
      f32x16 s0v, s1v;
#pragma unroll
      for (int r = 0; r < 16; ++r) { s0v[r] = 0.f; s1v[r] = 0.f; }
      __builtin_amdgcn_s_setprio(1);
#pragma unroll
      for (int ksl = 0; ksl < 4; ++ksl) {
        const s16x8 kf = *(const s16x8*)(Kc + rbyte + (((2 * ksl + hi) ^ xsw) << 4));
        s0v = __builtin_amdgcn_mfma_f32_32x32x16_bf16(kf, qf[ksl], s0v, 0, 0, 0);
      }
      if (two) {
#pragma unroll
        for (int ksl = 0; ksl < 4; ++ksl) {
          const s16x8 kf = *(const s16x8*)(Kc + 4096 + rbyte + (((2 * ksl + hi) ^ xsw) << 4));
          s1v = __builtin_amdgcn_mfma_f32_32x32x16_bf16(kf, qf[ksl], s1v, 0, 0, 0);
        }
      }
      __builtin_amdgcn_s_setprio(0);

      // ---- causal mask on diagonal tile ----
      if (kvb == diag) {
        const int thr = woff + l31;
#pragma unroll
        for (int r = 0; r < 16; ++r) {
          const int kvl = 4 * hi + (r & 3) + 8 * (r >> 2);
          if (kvl > thr) s0v[r] = -__builtin_inff();
          if (two && kvl + 32 > thr) s1v[r] = -__builtin_inff();
        }
      }

      // ---- online softmax, per-lane ----
      float mloc = s0v[0];
#pragma unroll
      for (int r = 1; r < 16; ++r) mloc = fmaxf(mloc, s0v[r]);
      if (two) {
#pragma unroll
        for (int r = 0; r < 16; ++r) mloc = fmaxf(mloc, s1v[r]);
      }
      mloc = fmaxf(mloc, __shfl_xor(mloc, 32));

      const bool needfull = !((mloc - mrun) * CEXP <= 8.0f);
      if (__any(needfull)) {
        const float newm = fmaxf(mrun, mloc);
        const float sc = fexp2((mrun - newm) * CEXP);
        mrun = newm;
        lrun *= sc;
        o0v *= sc;
        o1v *= sc;
      }
      const float msc = mrun * CEXP;

      float rs = 0.0f;
      u32 pd0[8], pd1[8];
#pragma unroll
      for (int ri = 0; ri < 8; ++ri) {
        const float p0 = fexp2(__builtin_fmaf(s0v[2 * ri], CEXP, -msc));
        const float p1 = fexp2(__builtin_fmaf(s0v[2 * ri + 1], CEXP, -msc));
        rs += p0 + p1;
        pd0[ri] = cvtpk(p0, p1);
      }
      if (two) {
#pragma unroll
        for (int ri = 0; ri < 8; ++ri) {
          const float p0 = fexp2(__builtin_fmaf(s1v[2 * ri], CEXP, -msc));
          const float p1 = fexp2(__builtin_fmaf(s1v[2 * ri + 1], CEXP, -msc));
          rs += p0 + p1;
          pd1[ri] = cvtpk(p0, p1);
        }
      }
      rs += __shfl_xor(rs, 32);
      lrun += rs;

      // ---- PV: rebuild B-fragments in-register, accumulate O^T ----
      __builtin_amdgcn_s_setprio(1);
#pragma unroll
      for (int kk = 0; kk < 4; ++kk) {
        if (kk >= 2 && !two) break;
        u32 x0, y0, x1, y1;
        if (kk == 0)      { x0 = pd0[0]; y0 = pd0[2]; x1 = pd0[1]; y1 = pd0[3]; }
        else if (kk == 1) { x0 = pd0[4]; y0 = pd0[6]; x1 = pd0[5]; y1 = pd0[7]; }
        else if (kk == 2) { x0 = pd1[0]; y0 = pd1[2]; x1 = pd1[1]; y1 = pd1[3]; }
        else              { x0 = pd1[4]; y0 = pd1[6]; x1 = pd1[5]; y1 = pd1[7]; }
        asm volatile("v_permlane32_swap_b32 %0, %1" : "+v"(x0), "+v"(y0));
        asm volatile("v_permlane32_swap_b32 %0, %1" : "+v"(x1), "+v"(y1));
        u32 pw[4] = {x0, x1, y0, y1};
        const s16x8 pf = *(const s16x8*)pw;
        const s16x8 vf0 = *(const s16x8*)(Vc + rbyte + (((2 * kk + hi) ^ xsw) << 4));
        const s16x8 vf1 = *(const s16x8*)(Vc + 4096 + rbyte + (((2 * kk + hi) ^ xsw) << 4));
        o0v = __builtin_amdgcn_mfma_f32_32x32x16_bf16(vf0, pf, o0v, 0, 0, 0);
        o1v = __builtin_amdgcn_mfma_f32_32x32x16_bf16(vf1, pf, o1v, 0, 0, 0);
      }
      __builtin_amdgcn_s_setprio(0);
    }

    if (havenext) {                       // write-late into the other buffer set
      const int nxt = cur ^ 1;
      *(s16x8*)(smem + nxt * 16384 + dst_off) = ke;
      *(s16x8*)(smem + nxt * 16384 + 8192 + dst_off) = ko;
      *(s16x8*)(smem + 32768 + nxt * 16384 + dst_off) = ve;
      *(s16x8*)(smem + 32768 + nxt * 16384 + 8192 + dst_off) = vo;
    }
    cur ^= 1;
  }

  // ---- merge kv-split partials (reuse LDS) ----
  __syncthreads();
  float* Omrg = (float*)smem;                   // [qw][32][64] = 32 KB
  float* Mm = (float*)(smem + 32768);           // [qw][64]
  float* Lm = (float*)(smem + 32768 + 1024);    // [qw][64]
  if (kvg == 1) {
#pragma unroll
    for (int r = 0; r < 16; ++r) {
      Omrg[(qw * 32 + r) * 64 + lane] = o0v[r];
      Omrg[(qw * 32 + 16 + r) * 64 + lane] = o1v[r];
    }
    Mm[qw * 64 + lane] = mrun;
    Lm[qw * 64 + lane] = lrun;
  }
  __syncthreads();
  if (kvg == 0) {
    const float mA = Mm[qw * 64 + lane];
    const float lA = Lm[qw * 64 + lane];
    const float m2 = fmaxf(mrun, mA);
    const float sB = fexp2((mrun - m2) * CEXP);
    const float sA = fexp2((mA - m2) * CEXP);
    const float linv = 1.0f / (lrun * sB + lA * sA);
    u16* orow = o + (size_t)(b * T_ + wrow0 + l31) * DIM_ + h * 64;
#pragma unroll
    for (int ri = 0; ri < 8; ++ri) {
      const int dbase0 = 4 * hi + 8 * (ri >> 1) + 2 * (ri & 1);
      const float a0 = (o0v[2 * ri] * sB + Omrg[(qw * 32 + 2 * ri) * 64 + lane] * sA) * linv;
      const float a1 = (o0v[2 * ri + 1] * sB + Omrg[(qw * 32 + 2 * ri + 1) * 64 + lane] * sA) * linv;
      const float b0 = (o1v[2 * ri] * sB + Omrg[(qw * 32 + 16 + 2 * ri) * 64 + lane] * sA) * linv;
      const float b1 = (o1v[2 * ri + 1] * sB + Omrg[(qw * 32 + 16 + 2 * ri + 1) * 64 + lane] * sA) * linv;
      *(u32*)(orow + dbase0) = cvtpk(a0, a1);
      *(u32*)(orow + 32 + dbase0) = cvtpk(b0, b1);
    }
  }
}

// ---------------- launch ----------------
extern "C" void kernel_launch(void* const* d_in, const int* in_sizes, int n_in,
                              void* d_out, int out_size, void* d_ws, size_t ws_size,
                              hipStream_t stream) {
  const float* x = (const float*)d_in[0];
  const float* w_qkv = (const float*)d_in[1];
  const float* w_out = (const float*)d_in[2];
  char* ws = (char*)d_ws;
  u16* xb    = (u16*)(ws + 0);          // 8,388,608
  u16* wqkvb = (u16*)(ws + 8388608);    // 6,291,456
  u16* woutb = (u16*)(ws + 14680064);   // 2,097,152
  u16* qkvb  = (u16*)(ws + 16777216);   // 25,165,824
  u16* vtb   = (u16*)(ws + 41943040);   // 8,388,608
  u16* attno = (u16*)(ws + 50331648);   // 8,388,608

  cvt_f32_bf16<<<4096, 256, 0, stream>>>(x, xb, 1048576);
  cvt_f32_bf16<<<3072, 256, 0, stream>>>(w_qkv, wqkvb, 786432);
  cvt_f32_bf16<<<1024, 256, 0, stream>>>(w_out, woutb, 262144);
  gemm_bt<0><<<dim3(24, 32), 256, 0, stream>>>(xb, wqkvb, qkvb, 4096, 3072, 1024);
  transpose_v<<<dim3(32, 32), 256, 0, stream>>>(qkvb, vtb);
  attn_fwd<<<512, 512, 0, stream>>>(qkvb, vtb, attno);
  gemm_bt<1><<<dim3(8, 32), 256, 0, stream>>>(attno, woutb, (float*)d_out, 4096, 1024, 1024);
}

// Round 7
// 127.915 us; speedup vs baseline: 1.3187x; 1.0307x over previous
//
#include <hip/hip_runtime.h>

#define DIM_ 1024
#define HEADS_ 16
#define HD_ 64
#define T_ 2048
#define BATCH_ 2
#define QKVN_ 3072

typedef unsigned short u16;
typedef unsigned int u32;
typedef float f32x4 __attribute__((ext_vector_type(4)));
typedef float f32x16 __attribute__((ext_vector_type(16)));
typedef short s16x8 __attribute__((ext_vector_type(8)));
typedef unsigned short u16x4 __attribute__((ext_vector_type(4)));

__device__ __forceinline__ u16 f2bf(float f) {
  unsigned u = __float_as_uint(f);
  u += 0x7fffu + ((u >> 16) & 1u);
  return (u16)(u >> 16);
}

__device__ __forceinline__ float fexp2(float x) {
  float r;
  asm("v_exp_f32 %0, %1" : "=v"(r) : "v"(x));
  return r;
}

__device__ __forceinline__ u32 cvtpk(float a, float b) {
  u32 r;
  asm("v_cvt_pk_bf16_f32 %0, %1, %2" : "=v"(r) : "v"(a), "v"(b));
  return r;
}

// ---------------- fused fp32 -> bf16 conversion (x | w_qkv | w_out) ----------------
// outputs are contiguous in ws: xb(1048576 f4) ++ wqkvb(786432 f4) ++ woutb(262144 f4)
__global__ __launch_bounds__(256) void cvt_all(const float* __restrict__ x,
                                               const float* __restrict__ wqkv,
                                               const float* __restrict__ wout,
                                               u16* __restrict__ outbase) {
  int i = blockIdx.x * 256 + threadIdx.x;   // [0, 2097152)
  const float4* src;
  int off;
  if (i < 1048576) { src = (const float4*)x; off = i; }
  else if (i < 1835008) { src = (const float4*)wqkv; off = i - 1048576; }
  else { src = (const float4*)wout; off = i - 1835008; }
  float4 v = src[off];
  u16x4 o;
  o.x = f2bf(v.x); o.y = f2bf(v.y); o.z = f2bf(v.z); o.w = f2bf(v.w);
  reinterpret_cast<u16x4*>(outbase)[i] = o;
}

// ---------------- async global->LDS helper ----------------
__device__ __forceinline__ void gld_lds16(const void* g, void* l) {
  auto gp = (__attribute__((address_space(1))) char*)(unsigned long long)g;
  auto lp = (__attribute__((address_space(3))) char*)(unsigned int)(unsigned long long)l;
  __builtin_amdgcn_global_load_lds(gp, lp, 16, 0, 0);
}

// ---------------- GEMM: C[M][N] = A[M][K] * B[N][K]^T (bf16 in, fp32 acc) ----------------
template <int OUTF32>
__global__ __launch_bounds__(256) void gemm_bt(const u16* __restrict__ A,
                                               const u16* __restrict__ B,
                                               void* __restrict__ Cv,
                                               int M, int N, int K) {
  __shared__ __align__(16) u16 As[128 * 32];
  __shared__ __align__(16) u16 Bs[128 * 32];
  const int tid = threadIdx.x;
  const int lane = tid & 63;
  const int w = tid >> 6;
  const int wr = w >> 1, wc = w & 1;
  const int lrow = lane & 15, kg = lane >> 4;
  const int nt = blockIdx.x, mt = blockIdx.y;
  const u16* Ag = A + (size_t)(mt * 128) * K;
  const u16* Bg = B + (size_t)(nt * 128) * K;

  f32x4 acc[4][4];
#pragma unroll
  for (int i = 0; i < 4; ++i)
#pragma unroll
    for (int j = 0; j < 4; ++j) {
      f32x4 z = {0.f, 0.f, 0.f, 0.f};
      acc[i][j] = z;
    }

  const int e0 = tid * 8;
  const int row0 = e0 >> 5, kc0 = e0 & 31;
  const int row1 = row0 + 64, kc1 = kc0;
  const int ldsoff0 = (tid & ~63) * 16;
  const int ldsoff1 = (256 + (tid & ~63)) * 16;

  for (int k0 = 0; k0 < K; k0 += 32) {
    gld_lds16(Ag + (size_t)row0 * K + k0 + kc0, (char*)As + ldsoff0);
    gld_lds16(Ag + (size_t)row1 * K + k0 + kc1, (char*)As + ldsoff1);
    gld_lds16(Bg + (size_t)row0 * K + k0 + kc0, (char*)Bs + ldsoff0);
    gld_lds16(Bg + (size_t)row1 * K + k0 + kc1, (char*)Bs + ldsoff1);
    __syncthreads();
    s16x8 a[4], b[4];
#pragma unroll
    for (int mf = 0; mf < 4; ++mf)
      a[mf] = *(const s16x8*)&As[(wr * 64 + mf * 16 + lrow) * 32 + 8 * kg];
#pragma unroll
    for (int nf = 0; nf < 4; ++nf)
      b[nf] = *(const s16x8*)&Bs[(wc * 64 + nf * 16 + lrow) * 32 + 8 * kg];
#pragma unroll
    for (int mf = 0; mf < 4; ++mf)
#pragma unroll
      for (int nf = 0; nf < 4; ++nf)
        acc[mf][nf] = __builtin_amdgcn_mfma_f32_16x16x32_bf16(a[mf], b[nf], acc[mf][nf], 0, 0, 0);
    __syncthreads();
  }

#pragma unroll
  for (int mf = 0; mf < 4; ++mf)
#pragma unroll
    for (int nf = 0; nf < 4; ++nf)
#pragma unroll
      for (int j = 0; j < 4; ++j) {
        int r = mt * 128 + wr * 64 + mf * 16 + 4 * kg + j;
        int c = nt * 128 + wc * 64 + nf * 16 + lrow;
        float v = acc[mf][nf][j];
        if (OUTF32) ((float*)Cv)[(size_t)r * N + c] = v;
        else        ((u16*)Cv)[(size_t)r * N + c] = f2bf(v);
      }
}

// ---------------- V transpose: vt[b][h][d][t] = qkv[b*T+t][2048 + h*64 + d] ----------------
__global__ __launch_bounds__(256) void transpose_v(const u16* __restrict__ qkv,
                                                   u16* __restrict__ vt) {
  const int tt = blockIdx.x, bh = blockIdx.y;
  const int b = bh >> 4, h = bh & 15;
  const int d = threadIdx.x & 63;
  const int t16 = threadIdx.x >> 6;
  const int tbase = tt * 64 + t16 * 16;
  u16 tmp[16];
#pragma unroll
  for (int i = 0; i < 16; ++i)
    tmp[i] = qkv[(size_t)(b * T_ + tbase + i) * QKVN_ + 2048 + h * 64 + d];
  u16* dst = vt + (size_t)(bh * 64 + d) * T_ + tbase;
  *(s16x8*)dst = *(const s16x8*)tmp;
  *(s16x8*)(dst + 8) = *(const s16x8*)(tmp + 8);
}

// ---------------- causal flash attention (swapped 32x32 + kv-split-2, raw-barrier pipe) ----
// 512 blocks (16 qt desc x 32 bh), 512 threads = 4 q-waves x 2 kv-groups.
// Raw s_barrier + lgkmcnt(0) only: global prefetch loads stay in flight across the
// barrier (no vmcnt drain); compiler's auto-vmcnt wait lands at the write-late ds_write.
__global__ __launch_bounds__(512, 4) void attn_fwd(const u16* __restrict__ qkv,
                                                   const u16* __restrict__ vt,
                                                   u16* __restrict__ o) {
  const int gid = blockIdx.x;
  const int qt = 15 - (gid >> 5);      // long blocks first
  const int bh = gid & 31;
  const int b = bh >> 4, h = bh & 15;
  const int tid = threadIdx.x;
  const int lane = tid & 63;
  const int qw = (tid >> 6) & 3;
  const int kvg = tid >> 8;
  const int l31 = lane & 31, hi = lane >> 5;
  const int qbase = qt * 128;
  const int wrow0 = qbase + qw * 32;
  const int wmax = wrow0 + 31;
  const int woff = wrow0 & 63;
  const int diag = wrow0 & ~63;

  // K: smem + buf*16384 + par*8192 ; V: smem + 32768 + buf*16384 + par*8192
  __shared__ __align__(16) char smem[65536];

  // staging: thread -> one 16B chunk in each of {K,V} x {even,odd} tiles
  const int row_s = tid >> 3, slot_s = tid & 7;
  const u16* Kbase = qkv + (size_t)(b * T_) * QKVN_ + 1024 + h * 64;
  const u16* Vbase = vt + (size_t)(bh * 64) * T_;
  const u16* Kg = Kbase + (size_t)row_s * QKVN_ + slot_s * 8;   // + kvb*QKVN_
  const u16* Vg = Vbase + (size_t)row_s * T_ + slot_s * 8;      // + kvb
  const int dst_off = row_s * 128 + ((slot_s ^ (row_s & 7)) << 4);

  // Q fragments: lane (l31,hi) holds Q[wrow0+l31][16*ksl + 8*hi .. +8]
  s16x8 qf[4];
  {
    const u16* qp = qkv + (size_t)(b * T_ + wrow0 + l31) * QKVN_ + h * 64 + 8 * hi;
#pragma unroll
    for (int ksl = 0; ksl < 4; ++ksl)
      qf[ksl] = *(const s16x8*)(qp + 16 * ksl);
  }

  const int rbyte = l31 * 128;
  const int xsw = l31 & 7;

  f32x16 o0v, o1v;
#pragma unroll
  for (int r = 0; r < 16; ++r) { o0v[r] = 0.f; o1v[r] = 0.f; }
  float mrun = -__builtin_inff(), lrun = 0.0f;

  const float CEXP = 0.18033688011112042f;  // (1/8) * log2(e)
  const int nrt = qt + 1;                   // rounds; tiles per round: 2

  // prologue: stage round 0 (tiles 0 and 1)
  *(s16x8*)(smem + dst_off)          = *(const s16x8*)Kg;
  *(s16x8*)(smem + 8192 + dst_off)   = *(const s16x8*)(Kg + (size_t)64 * QKVN_);
  *(s16x8*)(smem + 32768 + dst_off)  = *(const s16x8*)Vg;
  *(s16x8*)(smem + 40960 + dst_off)  = *(const s16x8*)(Vg + 64);

  int cur = 0;
  for (int rt = 0; rt < nrt; ++rt) {
    const int kvb = (2 * rt + kvg) * 64;
    const bool havenext = (rt + 1 < nrt);
    s16x8 ke, ko, ve, vo;
    if (havenext) {                       // issue next-round loads; stay in flight
      const int nb = (2 * rt + 2) * 64;
      ke = *(const s16x8*)(Kg + (size_t)nb * QKVN_);
      ko = *(const s16x8*)(Kg + (size_t)(nb + 64) * QKVN_);
      ve = *(const s16x8*)(Vg + nb);
      vo = *(const s16x8*)(Vg + nb + 64);
    }
    // raw barrier: drain LDS ops only (writes from prev round), NOT vmcnt
    asm volatile("s_waitcnt lgkmcnt(0)" ::: "memory");
    __builtin_amdgcn_s_barrier();
    __builtin_amdgcn_sched_barrier(0);

    if (kvb <= wmax) {
      const char* Kc = smem + cur * 16384 + kvg * 8192;
      const char* Vc = smem + 32768 + cur * 16384 + kvg * 8192;
      const bool two = !(kvb == diag && woff == 0);

      // ---- QK^T (swapped): lane holds q = wrow0+l31 ----
      f32x16 s0v, s1v;
#pragma unroll
      for (int r = 0; r < 16; ++r) { s0v[r] = 0.f; s1v[r] = 0.f; }
      __builtin_amdgcn_s_setprio(1);
#pragma unroll
      for (int ksl = 0; ksl < 4; ++ksl) {
        const s16x8 kf = *(const s16x8*)(Kc + rbyte + (((2 * ksl + hi) ^ xsw) << 4));
        s0v = __builtin_amdgcn_mfma_f32_32x32x16_bf16(kf, qf[ksl], s0v, 0, 0, 0);
      }
      if (two) {
#pragma unroll
        for (int ksl = 0; ksl < 4; ++ksl) {
          const s16x8 kf = *(const s16x8*)(Kc + 4096 + rbyte + (((2 * ksl + hi) ^ xsw) << 4));
          s1v = __builtin_amdgcn_mfma_f32_32x32x16_bf16(kf, qf[ksl], s1v, 0, 0, 0);
        }
      }
      __builtin_amdgcn_s_setprio(0);

      // ---- causal mask on diagonal tile ----
      if (kvb == diag) {
        const int thr = woff + l31;
#pragma unroll
        for (int r = 0; r < 16; ++r) {
          const int kvl = 4 * hi + (r & 3) + 8 * (r >> 2);
          if (kvl > thr) s0v[r] = -__builtin_inff();
          if (two && kvl + 32 > thr) s1v[r] = -__builtin_inff();
        }
      }

      // ---- online softmax, per-lane ----
      float mloc = s0v[0];
#pragma unroll
      for (int r = 1; r < 16; ++r) mloc = fmaxf(mloc, s0v[r]);
      if (two) {
#pragma unroll
        for (int r = 0; r < 16; ++r) mloc = fmaxf(mloc, s1v[r]);
      }
      mloc = fmaxf(mloc, __shfl_xor(mloc, 32));

      const bool needfull = !((mloc - mrun) * CEXP <= 8.0f);
      if (__any(needfull)) {
        const float newm = fmaxf(mrun, mloc);
        const float sc = fexp2((mrun - newm) * CEXP);
        mrun = newm;
        lrun *= sc;
        o0v *= sc;
        o1v *= sc;
      }
      const float msc = mrun * CEXP;

      float rs = 0.0f;
      u32 pd0[8], pd1[8];
#pragma unroll
      for (int ri = 0; ri < 8; ++ri) {
        const float p0 = fexp2(__builtin_fmaf(s0v[2 * ri], CEXP, -msc));
        const float p1 = fexp2(__builtin_fmaf(s0v[2 * ri + 1], CEXP, -msc));
        rs += p0 + p1;
        pd0[ri] = cvtpk(p0, p1);
      }
      if (two) {
#pragma unroll
        for (int ri = 0; ri < 8; ++ri) {
          const float p0 = fexp2(__builtin_fmaf(s1v[2 * ri], CEXP, -msc));
          const float p1 = fexp2(__builtin_fmaf(s1v[2 * ri + 1], CEXP, -msc));
          rs += p0 + p1;
          pd1[ri] = cvtpk(p0, p1);
        }
      }
      rs += __shfl_xor(rs, 32);
      lrun += rs;

      // ---- PV: rebuild B-fragments in-register, accumulate O^T ----
      __builtin_amdgcn_s_setprio(1);
#pragma unroll
      for (int kk = 0; kk < 4; ++kk) {
        if (kk >= 2 && !two) break;
        u32 x0, y0, x1, y1;
        if (kk == 0)      { x0 = pd0[0]; y0 = pd0[2]; x1 = pd0[1]; y1 = pd0[3]; }
        else if (kk == 1) { x0 = pd0[4]; y0 = pd0[6]; x1 = pd0[5]; y1 = pd0[7]; }
        else if (kk == 2) { x0 = pd1[0]; y0 = pd1[2]; x1 = pd1[1]; y1 = pd1[3]; }
        else              { x0 = pd1[4]; y0 = pd1[6]; x1 = pd1[5]; y1 = pd1[7]; }
        asm volatile("v_permlane32_swap_b32 %0, %1" : "+v"(x0), "+v"(y0));
        asm volatile("v_permlane32_swap_b32 %0, %1" : "+v"(x1), "+v"(y1));
        u32 pw[4] = {x0, x1, y0, y1};
        const s16x8 pf = *(const s16x8*)pw;
        const s16x8 vf0 = *(const s16x8*)(Vc + rbyte + (((2 * kk + hi) ^ xsw) << 4));
        const s16x8 vf1 = *(const s16x8*)(Vc + 4096 + rbyte + (((2 * kk + hi) ^ xsw) << 4));
        o0v = __builtin_amdgcn_mfma_f32_32x32x16_bf16(vf0, pf, o0v, 0, 0, 0);
        o1v = __builtin_amdgcn_mfma_f32_32x32x16_bf16(vf1, pf, o1v, 0, 0, 0);
      }
      __builtin_amdgcn_s_setprio(0);
    }

    if (havenext) {                       // write-late into the other buffer set
      const int nxt = cur ^ 1;
      *(s16x8*)(smem + nxt * 16384 + dst_off) = ke;
      *(s16x8*)(smem + nxt * 16384 + 8192 + dst_off) = ko;
      *(s16x8*)(smem + 32768 + nxt * 16384 + dst_off) = ve;
      *(s16x8*)(smem + 32768 + nxt * 16384 + 8192 + dst_off) = vo;
    }
    cur ^= 1;
  }

  // ---- merge kv-split partials (reuse LDS) ----
  __syncthreads();
  float* Omrg = (float*)smem;                   // [qw][32][64] = 32 KB
  float* Mm = (float*)(smem + 32768);           // [qw][64]
  float* Lm = (float*)(smem + 32768 + 1024);    // [qw][64]
  if (kvg == 1) {
#pragma unroll
    for (int r = 0; r < 16; ++r) {
      Omrg[(qw * 32 + r) * 64 + lane] = o0v[r];
      Omrg[(qw * 32 + 16 + r) * 64 + lane] = o1v[r];
    }
    Mm[qw * 64 + lane] = mrun;
    Lm[qw * 64 + lane] = lrun;
  }
  __syncthreads();
  if (kvg == 0) {
    const float mA = Mm[qw * 64 + lane];
    const float lA = Lm[qw * 64 + lane];
    const float m2 = fmaxf(mrun, mA);
    const float sB = fexp2((mrun - m2) * CEXP);
    const float sA = fexp2((mA - m2) * CEXP);
    const float linv = 1.0f / (lrun * sB + lA * sA);
    u16* orow = o + (size_t)(b * T_ + wrow0 + l31) * DIM_ + h * 64;
#pragma unroll
    for (int ri = 0; ri < 8; ++ri) {
      const int dbase0 = 4 * hi + 8 * (ri >> 1) + 2 * (ri & 1);
      const float a0 = (o0v[2 * ri] * sB + Omrg[(qw * 32 + 2 * ri) * 64 + lane] * sA) * linv;
      const float a1 = (o0v[2 * ri + 1] * sB + Omrg[(qw * 32 + 2 * ri + 1) * 64 + lane] * sA) * linv;
      const float b0 = (o1v[2 * ri] * sB + Omrg[(qw * 32 + 16 + 2 * ri) * 64 + lane] * sA) * linv;
      const float b1 = (o1v[2 * ri + 1] * sB + Omrg[(qw * 32 + 16 + 2 * ri + 1) * 64 + lane] * sA) * linv;
      *(u32*)(orow + dbase0) = cvtpk(a0, a1);
      *(u32*)(orow + 32 + dbase0) = cvtpk(b0, b1);
    }
  }
}

// ---------------- launch ----------------
extern "C" void kernel_launch(void* const* d_in, const int* in_sizes, int n_in,
                              void* d_out, int out_size, void* d_ws, size_t ws_size,
                              hipStream_t stream) {
  const float* x = (const float*)d_in[0];
  const float* w_qkv = (const float*)d_in[1];
  const float* w_out = (const float*)d_in[2];
  char* ws = (char*)d_ws;
  u16* xb    = (u16*)(ws + 0);          // 8,388,608
  u16* wqkvb = (u16*)(ws + 8388608);    // 6,291,456
  u16* woutb = (u16*)(ws + 14680064);   // 2,097,152
  u16* qkvb  = (u16*)(ws + 16777216);   // 25,165,824
  u16* vtb   = (u16*)(ws + 41943040);   // 8,388,608
  u16* attno = (u16*)(ws + 50331648);   // 8,388,608

  cvt_all<<<8192, 256, 0, stream>>>(x, w_qkv, w_out, xb);
  gemm_bt<0><<<dim3(24, 32), 256, 0, stream>>>(xb, wqkvb, qkvb, 4096, 3072, 1024);
  transpose_v<<<dim3(32, 32), 256, 0, stream>>>(qkvb, vtb);
  attn_fwd<<<512, 512, 0, stream>>>(qkvb, vtb, attno);
  gemm_bt<1><<<dim3(8, 32), 256, 0, stream>>>(attno, woutb, (float*)d_out, 4096, 1024, 1024);
}